// Round 1
// baseline (2052.787 us; speedup 1.0000x reference)
//
#include <hip/hip_runtime.h>
#include <cstddef>
#include <cstdint>

// ---------------------------------------------------------------------------
// Masked GCN autoencoder, MI355X.
// All matmuls via MFMA bf16 16x16x32 with 3-term split (ah*bh + ah*bl + al*bh)
// => ~fp32 precision.  A-side staged fp32 in LDS (adj read directly, no copy),
// split to bf16 in registers.  B-side pre-transposed + pre-split bf16 planes
// (BT[N][Kpad32], zero-padded), so the GEMM K-loop needs no remainder path
// (A addresses are clamped; garbage lanes multiply B's zero pad).
// ---------------------------------------------------------------------------

typedef __attribute__((ext_vector_type(8))) short bf16x8;
typedef __attribute__((ext_vector_type(4))) float f32x4;

__device__ __forceinline__ unsigned short f2bf(float f) {   // RTNE fp32->bf16
  unsigned u = __float_as_uint(f);
  return (unsigned short)((u + 0x7fffu + ((u >> 16) & 1u)) >> 16);
}
__device__ __forceinline__ float bf2f(unsigned short s) {
  return __uint_as_float(((unsigned)s) << 16);
}

__device__ __forceinline__ void load_lds16(const void* g, void* l) {
  __builtin_amdgcn_global_load_lds(
      (const __attribute__((address_space(1))) void*)g,
      (__attribute__((address_space(3))) void*)l, 16, 0, 0);
}

// ---------------------------------------------------------------------------
// GEMM: C[M,N] = A[M,K](fp32, lda) @ B  where B is given as transposed planes
// Bh/Bl = bf16 planes of BT[N][ldb] (ldb = K rounded up to 32, zero-padded).
// Writes fp32 partials Cp[part][M][N]; split-K via blockIdx.z.
// Tile 128x128, BK=32, 256 threads (4 waves, 2x2), XOR-swizzled LDS.
// ---------------------------------------------------------------------------
__global__ __launch_bounds__(256, 2) void k_gemm_split(
    const float* __restrict__ A, int lda,
    const unsigned short* __restrict__ Bh, const unsigned short* __restrict__ Bl,
    int ldb, float* __restrict__ Cp, int M, int N, int K, int parts)
{
  __shared__ float          As [128 * 32];   // 16 KiB
  __shared__ unsigned short Bhs[128 * 32];   //  8 KiB
  __shared__ unsigned short Bls[128 * 32];   //  8 KiB

  const int t    = threadIdx.x;
  const int lane = t & 63;
  const int w    = t >> 6;
  const int m0   = blockIdx.x * 128;
  const int n0   = blockIdx.y * 128;

  const int Ksteps = (K + 31) >> 5;
  const int chunk  = (Ksteps + parts - 1) / parts;
  const int k0     = blockIdx.z * chunk;
  const int k1     = min(k0 + chunk, Ksteps);
  const int K4m16  = K * 4 - 16;             // last safe 16B column offset

  // ---- staging precompute: A (4 slots/thread), fp32 rows of 128B ----
  const char* arow[4]; int acsw[4]; char* aldst[4];
#pragma unroll
  for (int i = 0; i < 4; ++i) {
    int o   = w * 4096 + i * 1024 + lane * 16;  // byte offset in 16KiB tile
    int row = o >> 7;                            // 0..127
    int k2  = o & 127;                           // {0,16,...,112}
    int rg  = m0 + row; if (rg > M - 1) rg = M - 1;   // row clamp (safe OOB)
    acsw[i] = k2 ^ ((row & 7) << 4);             // source pre-swizzle
    arow[i] = (const char*)A + (size_t)rg * lda * 4;
    aldst[i] = (char*)As + (o - lane * 16);      // wave-uniform LDS base
  }
  // ---- staging precompute: B planes (2 slots/plane/thread), bf16 rows 64B --
  const char* browh[2]; const char* browl[2]; int bcsw[2];
  char* bldsth[2]; char* bldstl[2];
#pragma unroll
  for (int i = 0; i < 2; ++i) {
    int o   = w * 2048 + i * 1024 + lane * 16;
    int row = o >> 6;                            // 0..127
    int k2  = o & 63;                            // {0,16,32,48}
    bcsw[i] = k2 ^ (((row >> 1) & 3) << 4);
    browh[i] = (const char*)Bh + (size_t)(n0 + row) * ldb * 2;
    browl[i] = (const char*)Bl + (size_t)(n0 + row) * ldb * 2;
    bldsth[i] = (char*)Bhs + (o - lane * 16);
    bldstl[i] = (char*)Bls + (o - lane * 16);
  }

  // ---- fragment LDS read offsets (kk-invariant) ----
  const int r16 = lane & 15, kh = lane >> 4;
  const int wr = (w >> 1) * 64, wc = (w & 1) * 64;
  int aoff0[4], aoff1[4], boff[4];
#pragma unroll
  for (int m = 0; m < 4; ++m) {
    int row = wr + m * 16 + r16;
    int s   = (row & 7) << 4;
    aoff0[m] = row * 128 + ((kh * 32) ^ s);
    aoff1[m] = row * 128 + ((kh * 32 + 16) ^ s);
  }
#pragma unroll
  for (int n = 0; n < 4; ++n) {
    int row = wc + n * 16 + r16;
    boff[n] = row * 64 + ((kh * 16) ^ (((row >> 1) & 3) << 4));
  }

  f32x4 acc[4][4];
#pragma unroll
  for (int m = 0; m < 4; ++m)
#pragma unroll
    for (int n = 0; n < 4; ++n) acc[m][n] = (f32x4){0.f, 0.f, 0.f, 0.f};

  for (int kk = k0; kk < k1; ++kk) {
    // stage A (fp32) + B planes (bf16) via async global->LDS, width 16
#pragma unroll
    for (int i = 0; i < 4; ++i) {
      int colb = kk * 128 + acsw[i];
      if (colb > K4m16) colb = K4m16;            // clamp: B pad zeros kill it
      load_lds16(arow[i] + colb, aldst[i]);
    }
#pragma unroll
    for (int i = 0; i < 2; ++i) {
      int colb = kk * 64 + bcsw[i];
      load_lds16(browh[i] + colb, bldsth[i]);
      load_lds16(browl[i] + colb, bldstl[i]);
    }
    __syncthreads();   // compiler drains vmcnt before s_barrier -> tiles ready

    bf16x8 ah[4], al[4], bh[4], bl[4];
#pragma unroll
    for (int m = 0; m < 4; ++m) {
      f32x4 q0 = *(const f32x4*)((const char*)As + aoff0[m]);
      f32x4 q1 = *(const f32x4*)((const char*)As + aoff1[m]);
#pragma unroll
      for (int j = 0; j < 4; ++j) {
        float f = q0[j];
        unsigned short hb = f2bf(f);
        ah[m][j] = (short)hb;
        al[m][j] = (short)f2bf(f - bf2f(hb));
        f = q1[j];
        hb = f2bf(f);
        ah[m][j + 4] = (short)hb;
        al[m][j + 4] = (short)f2bf(f - bf2f(hb));
      }
    }
#pragma unroll
    for (int n = 0; n < 4; ++n) {
      bh[n] = *(const bf16x8*)((const char*)Bhs + boff[n]);
      bl[n] = *(const bf16x8*)((const char*)Bls + boff[n]);
    }
#pragma unroll
    for (int m = 0; m < 4; ++m)
#pragma unroll
      for (int n = 0; n < 4; ++n) {
        acc[m][n] = __builtin_amdgcn_mfma_f32_16x16x32_bf16(ah[m], bh[n], acc[m][n], 0, 0, 0);
        acc[m][n] = __builtin_amdgcn_mfma_f32_16x16x32_bf16(ah[m], bl[n], acc[m][n], 0, 0, 0);
        acc[m][n] = __builtin_amdgcn_mfma_f32_16x16x32_bf16(al[m], bh[n], acc[m][n], 0, 0, 0);
      }
    __syncthreads();   // protect LDS before next stage
  }

  float* Cpart = Cp + (size_t)blockIdx.z * (size_t)M * N;
#pragma unroll
  for (int m = 0; m < 4; ++m) {
    int rbase = m0 + wr + m * 16 + kh * 4;
#pragma unroll
    for (int n = 0; n < 4; ++n) {
      int c = n0 + wc + n * 16 + r16;
#pragma unroll
      for (int j = 0; j < 4; ++j) {
        int r = rbase + j;
        if (r < M && c < N) Cpart[(size_t)r * N + c] = acc[m][n][j];
      }
    }
  }
}

// ---------------------------------------------------------------------------
// h = x * mask, written to padded [10000][pcols] fp32 (zero pad cols)
// ---------------------------------------------------------------------------
__global__ void k_mulmask_pad(const float* __restrict__ x, const float* __restrict__ mask,
                              float* __restrict__ h, int cols, int pcols)
{
  int c = blockIdx.x * 256 + threadIdx.x;
  int r = blockIdx.y;
  if (c >= pcols) return;
  float v = 0.f;
  if (c < cols) {
    size_t i = (size_t)r * cols + c;
    v = x[i] * mask[i];
  }
  h[(size_t)r * pcols + c] = v;
}

// ---------------------------------------------------------------------------
// Sum partials (no bias here for weights: parts==1, P==W), transpose, split
// into bf16 hi/lo planes T[rowsOut][ldk].  Zero-fills r>=M (K pad) and c>=N.
// block (32,8)
// ---------------------------------------------------------------------------
__global__ void k_transpose_split(const float* __restrict__ P, int parts, int M, int N,
                                  unsigned short* __restrict__ Th, unsigned short* __restrict__ Tl,
                                  int ldk, int rowsOut)
{
  __shared__ float tile[32][33];
  int kb = blockIdx.x * 32;   // source-row block (-> T col)
  int nb = blockIdx.y * 32;   // source-col block (-> T row)
  int tx = threadIdx.x, ty = threadIdx.y;
#pragma unroll
  for (int i = 0; i < 4; ++i) {
    int r = kb + ty + i * 8;
    int c = nb + tx;
    float v = 0.f;
    if (r < M && c < N) {
      size_t idx = (size_t)r * N + c;
      v = P[idx];
      for (int p = 1; p < parts; ++p) v += P[(size_t)p * M * N + idx];
    }
    tile[ty + i * 8][tx] = v;
  }
  __syncthreads();
#pragma unroll
  for (int i = 0; i < 4; ++i) {
    int tr = nb + ty + i * 8;
    int tc = kb + tx;
    if (tr < rowsOut && tc < ldk) {
      float v = tile[tx][ty + i * 8];
      unsigned short hb = f2bf(v);
      unsigned short lb = f2bf(v - bf2f(hb));
      size_t o = (size_t)tr * ldk + tc;
      Th[o] = hb;
      Tl[o] = lb;
    }
  }
}

// ---------------------------------------------------------------------------
// out = relu?(sum parts + bias), fp32 row-major [M][N]
// ---------------------------------------------------------------------------
__global__ void k_finish_rowmajor(const float* __restrict__ P, int parts,
                                  const float* __restrict__ bias, int relu,
                                  float* __restrict__ out, int M, int N)
{
  int c = blockIdx.x * 256 + threadIdx.x;
  int r = blockIdx.y;
  if (c >= N) return;
  size_t idx = (size_t)r * N + c;
  float v = P[idx];
  for (int p = 1; p < parts; ++p) v += P[(size_t)p * M * N + idx];
  v += bias[c];
  if (relu) v = fmaxf(v, 0.f);
  out[idx] = v;
}

// ---------------------------------------------------------------------------
// z = (sum parts + bz) row-normalized; one block (128 thr) per row
// ---------------------------------------------------------------------------
__global__ void k_finish_z(const float* __restrict__ P, int parts,
                           const float* __restrict__ bz, float* __restrict__ zout)
{
  int r = blockIdx.x, c = threadIdx.x;
  size_t idx = (size_t)r * 128 + c;
  float v = P[idx];
  for (int p = 1; p < parts; ++p) v += P[(size_t)p * 10000 * 128 + idx];
  v += bz[c];
  float s = v * v;
#pragma unroll
  for (int off = 32; off > 0; off >>= 1) s += __shfl_down(s, off, 64);
  __shared__ float red[2];
  if ((c & 63) == 0) red[c >> 6] = s;
  __syncthreads();
  float inv = 1.f / fmaxf(sqrtf(red[0] + red[1]), 1e-12f);
  zout[idx] = v * inv;
}

// ---------------------------------------------------------------------------
// x_hat = (P + bd2) * mask
// ---------------------------------------------------------------------------
__global__ void k_finish_xhat(const float* __restrict__ P, const float* __restrict__ bd2,
                              const float* __restrict__ mask, float* __restrict__ out)
{
  int c = blockIdx.x * 256 + threadIdx.x;
  int r = blockIdx.y;
  if (c >= 2000) return;
  size_t idx = (size_t)r * 2000 + c;
  out[idx] = (P[idx] + bd2[c]) * mask[idx];
}

// ---------------------------------------------------------------------------
extern "C" void kernel_launch(void* const* d_in, const int* in_sizes, int n_in,
                              void* d_out, int out_size, void* d_ws, size_t ws_size,
                              hipStream_t stream)
{
  (void)in_sizes; (void)n_in; (void)out_size; (void)ws_size;
  const float* x    = (const float*)d_in[0];
  const float* adj  = (const float*)d_in[1];
  const float* mask = (const float*)d_in[2];
  const float* We0  = (const float*)d_in[3];
  const float* be0  = (const float*)d_in[4];
  const float* We1  = (const float*)d_in[5];
  const float* be1  = (const float*)d_in[6];
  const float* Wz   = (const float*)d_in[7];
  const float* bz   = (const float*)d_in[8];
  const float* Wd0  = (const float*)d_in[9];
  const float* bd0  = (const float*)d_in[10];
  const float* Wd1  = (const float*)d_in[11];
  const float* bd1  = (const float*)d_in[12];
  const float* Wd2  = (const float*)d_in[13];
  const float* bd2  = (const float*)d_in[14];

  char* wsp = (char*)d_ws;
  size_t off = 0;
  auto alloc = [&](size_t bytes) -> char* {
    char* p = wsp + off; off += (bytes + 255) & ~(size_t)255; return p;
  };

  float* h = (float*)alloc((size_t)10000 * 2016 * 4);        // 80.64 MB (reused as G8 partial)
  unsigned short* We0Th = (unsigned short*)alloc((size_t)512 * 2016 * 2);
  unsigned short* We0Tl = (unsigned short*)alloc((size_t)512 * 2016 * 2);
  unsigned short* We1Th = (unsigned short*)alloc((size_t)256 * 512 * 2);
  unsigned short* We1Tl = (unsigned short*)alloc((size_t)256 * 512 * 2);
  unsigned short* WzTh  = (unsigned short*)alloc((size_t)128 * 256 * 2);
  unsigned short* WzTl  = (unsigned short*)alloc((size_t)128 * 256 * 2);
  unsigned short* Wd0Th = (unsigned short*)alloc((size_t)256 * 128 * 2);
  unsigned short* Wd0Tl = (unsigned short*)alloc((size_t)256 * 128 * 2);
  unsigned short* Wd1Th = (unsigned short*)alloc((size_t)512 * 256 * 2);
  unsigned short* Wd1Tl = (unsigned short*)alloc((size_t)512 * 256 * 2);
  unsigned short* Wd2Th = (unsigned short*)alloc((size_t)2048 * 512 * 2);
  unsigned short* Wd2Tl = (unsigned short*)alloc((size_t)2048 * 512 * 2);
  unsigned short* t0Th  = (unsigned short*)alloc((size_t)512 * 10016 * 2);
  unsigned short* t0Tl  = (unsigned short*)alloc((size_t)512 * 10016 * 2);
  unsigned short* t1Th  = (unsigned short*)alloc((size_t)256 * 10016 * 2);
  unsigned short* t1Tl  = (unsigned short*)alloc((size_t)256 * 10016 * 2);
  unsigned short* tzTh  = (unsigned short*)alloc((size_t)128 * 10016 * 2);
  unsigned short* tzTl  = (unsigned short*)alloc((size_t)128 * 10016 * 2);
  float* h0    = (float*)alloc((size_t)10000 * 512 * 4);
  float* h1    = (float*)alloc((size_t)10000 * 256 * 4);
  float* d0b   = (float*)alloc((size_t)10000 * 256 * 4);
  float* d1b   = (float*)alloc((size_t)10000 * 512 * 4);
  float* arena = (float*)alloc((size_t)10000 * 512 * 4);     // max 20.48 MB of partials
  float* g8p   = h;                                          // reuse h after G0

  float* zout    = (float*)d_out;                            // [10000][128]
  float* xhat    = zout + (size_t)10000 * 128;               // [10000][2000]
  float* maskout = xhat + (size_t)10000 * 2000;              // [10000][2000]

  dim3 b256(256), b32x8(32, 8);

  // h = x*mask (padded K 2000->2016, zero pad)
  k_mulmask_pad<<<dim3(8, 10000), b256, 0, stream>>>(x, mask, h, 2000, 2016);

  // weight transposes + bf16 hi/lo split
  k_transpose_split<<<dim3(63, 16), b32x8, 0, stream>>>(We0, 1, 2000, 512, We0Th, We0Tl, 2016, 512);
  k_transpose_split<<<dim3(16, 8),  b32x8, 0, stream>>>(We1, 1, 512, 256, We1Th, We1Tl, 512, 256);
  k_transpose_split<<<dim3(8, 4),   b32x8, 0, stream>>>(Wz,  1, 256, 128, WzTh,  WzTl,  256, 128);
  k_transpose_split<<<dim3(4, 8),   b32x8, 0, stream>>>(Wd0, 1, 128, 256, Wd0Th, Wd0Tl, 128, 256);
  k_transpose_split<<<dim3(8, 16),  b32x8, 0, stream>>>(Wd1, 1, 256, 512, Wd1Th, Wd1Tl, 256, 512);
  k_transpose_split<<<dim3(16, 64), b32x8, 0, stream>>>(Wd2, 1, 512, 2000, Wd2Th, Wd2Tl, 512, 2048);

  // G0: t0 = h @ We0                         [10000,512]
  k_gemm_split<<<dim3(79, 4, 1), b256, 0, stream>>>(h, 2016, We0Th, We0Tl, 2016, arena, 10000, 512, 2016, 1);
  k_transpose_split<<<dim3(313, 16), b32x8, 0, stream>>>(arena, 1, 10000, 512, t0Th, t0Tl, 10016, 512);
  // G1: h0 = relu(adj @ t0 + be0)
  k_gemm_split<<<dim3(79, 4, 1), b256, 0, stream>>>(adj, 10000, t0Th, t0Tl, 10016, arena, 10000, 512, 10000, 1);
  k_finish_rowmajor<<<dim3(2, 10000), b256, 0, stream>>>(arena, 1, be0, 1, h0, 10000, 512);
  // G2: t1 = h0 @ We1                        [10000,256]
  k_gemm_split<<<dim3(79, 2, 1), b256, 0, stream>>>(h0, 512, We1Th, We1Tl, 512, arena, 10000, 256, 512, 1);
  k_transpose_split<<<dim3(313, 8), b32x8, 0, stream>>>(arena, 1, 10000, 256, t1Th, t1Tl, 10016, 256);
  // G3: h1 = relu(adj @ t1 + be1)   (split-K 2)
  k_gemm_split<<<dim3(79, 2, 2), b256, 0, stream>>>(adj, 10000, t1Th, t1Tl, 10016, arena, 10000, 256, 10000, 2);
  k_finish_rowmajor<<<dim3(1, 10000), b256, 0, stream>>>(arena, 2, be1, 1, h1, 10000, 256);
  // G4: tz = h1 @ Wz                         [10000,128]
  k_gemm_split<<<dim3(79, 1, 1), b256, 0, stream>>>(h1, 256, WzTh, WzTl, 256, arena, 10000, 128, 256, 1);
  k_transpose_split<<<dim3(313, 4), b32x8, 0, stream>>>(arena, 1, 10000, 128, tzTh, tzTl, 10016, 128);
  // G5: zraw = adj @ tz + bz        (split-K 4), then normalize -> d_out
  k_gemm_split<<<dim3(79, 1, 4), b256, 0, stream>>>(adj, 10000, tzTh, tzTl, 10016, arena, 10000, 128, 10000, 4);
  k_finish_z<<<dim3(10000), dim3(128), 0, stream>>>(arena, 4, bz, zout);
  // G6: d0 = relu(z @ Wd0 + bd0)             [10000,256]
  k_gemm_split<<<dim3(79, 2, 1), b256, 0, stream>>>(zout, 128, Wd0Th, Wd0Tl, 128, arena, 10000, 256, 128, 1);
  k_finish_rowmajor<<<dim3(1, 10000), b256, 0, stream>>>(arena, 1, bd0, 1, d0b, 10000, 256);
  // G7: d1 = relu(d0 @ Wd1 + bd1)            [10000,512]
  k_gemm_split<<<dim3(79, 4, 1), b256, 0, stream>>>(d0b, 256, Wd1Th, Wd1Tl, 256, arena, 10000, 512, 256, 1);
  k_finish_rowmajor<<<dim3(2, 10000), b256, 0, stream>>>(arena, 1, bd1, 1, d1b, 10000, 512);
  // G8: x_hat = (d1 @ Wd2 + bd2) * mask      [10000,2000]
  k_gemm_split<<<dim3(79, 16, 1), b256, 0, stream>>>(d1b, 512, Wd2Th, Wd2Tl, 512, g8p, 10000, 2000, 512, 1);
  k_finish_xhat<<<dim3(8, 10000), b256, 0, stream>>>(g8p, bd2, mask, xhat);

  // mask passthrough output
  hipMemcpyAsync(maskout, mask, (size_t)10000 * 2000 * 4, hipMemcpyDeviceToDevice, stream);
}

// Round 2
// 1628.753 us; speedup vs baseline: 1.2603x; 1.2603x over previous
//
#include <hip/hip_runtime.h>
#include <cstddef>
#include <cstdint>

// ---------------------------------------------------------------------------
// Masked GCN autoencoder, MI355X.  MFMA bf16 16x16x32, 3-term hi/lo split
// (~fp32 precision).  adj read fp32 + split in-register via v_cvt_pk_bf16_f32;
// all other operands pre-split into bf16 hi/lo planes by producer kernels.
// Split-K + XCD-chunked n-fast 1D grid for occupancy / L2-L3 locality.
// ---------------------------------------------------------------------------

typedef __attribute__((ext_vector_type(8))) short bf16x8;
typedef __attribute__((ext_vector_type(4))) float f32x4;

union BFU { bf16x8 v; unsigned u[4]; };

__device__ __forceinline__ unsigned short f2bf(float f) {   // RTNE fp32->bf16
  unsigned u = __float_as_uint(f);
  return (unsigned short)((u + 0x7fffu + ((u >> 16) & 1u)) >> 16);
}
__device__ __forceinline__ float bf2f(unsigned short s) {
  return __uint_as_float(((unsigned)s) << 16);
}

// pack bf16(f0),bf16(f1) -> ph ; residual pair -> pl  (RTNE, 6 VALU / 2 elems)
__device__ __forceinline__ void split_pair(float f0, float f1, unsigned& ph, unsigned& pl) {
  unsigned h;
  asm("v_cvt_pk_bf16_f32 %0, %1, %2" : "=v"(h) : "v"(f0), "v"(f1));
  float r0 = f0 - __uint_as_float(h << 16);
  float r1 = f1 - __uint_as_float(h & 0xffff0000u);
  unsigned l;
  asm("v_cvt_pk_bf16_f32 %0, %1, %2" : "=v"(l) : "v"(r0), "v"(r1));
  ph = h; pl = l;
}

__device__ __forceinline__ void load_lds16(const void* g, void* l) {
  __builtin_amdgcn_global_load_lds(
      (const __attribute__((address_space(1))) void*)g,
      (__attribute__((address_space(3))) void*)l, 16, 0, 0);
}

// ---------------------------------------------------------------------------
// GEMM: Cpart[part][M][N] = A[m-chunk of K] @ B.  B always pre-split planes
// BT[N][ldb] (bf16 hi/lo, K zero-padded to ldb).  A either fp32 (adj; split
// in-register) or pre-split planes like B.  Tile 128x128, BK=32, 4 waves.
// 1D grid = nbx*nby*parts, XCD-bijective chunked, n fastest (A-panel reuse).
// ---------------------------------------------------------------------------
template<bool AFP32>
__global__ __launch_bounds__(256, 3) void k_gemm(
    const float* __restrict__ Af, int K,
    const unsigned short* __restrict__ Aph, const unsigned short* __restrict__ Apl,
    int lda,
    const unsigned short* __restrict__ Bh, const unsigned short* __restrict__ Bl,
    int ldb,
    float* __restrict__ Cp, int M, int N,
    int Ksteps, int nbx, int nby, int kchunk)
{
  __shared__ __align__(16) char lds[32768];
  float*          As  = (float*)lds;                    // AFP32 path: 16 KiB
  unsigned short* Ahs = (unsigned short*)lds;           // plane path: 8 KiB
  unsigned short* Als = (unsigned short*)(lds + 8192);  //             8 KiB
  unsigned short* Bhs = (unsigned short*)(lds + 16384);
  unsigned short* Bls = (unsigned short*)(lds + 24576);

  const int t = threadIdx.x, lane = t & 63, w = t >> 6;

  // XCD-bijective chunked remap (m204 variant), then n-fast decomposition
  const int nwg = gridDim.x;
  const int q = nwg >> 3, r = nwg & 7;
  const int xcd = blockIdx.x & 7, loc = blockIdx.x >> 3;
  const int wg = (xcd < r ? xcd * (q + 1) : r * (q + 1) + (xcd - r) * q) + loc;
  const int n0   = (wg % nby) * 128;
  const int tmp  = wg / nby;
  const int m0   = (tmp % nbx) * 128;
  const int part = tmp / nbx;
  const int k0 = part * kchunk;
  const int k1 = min(k0 + kchunk, Ksteps);

  // ---- B staging precompute (2 slots/plane/thread) ----
  const char* browh[2]; const char* browl[2]; int bcsw[2]; char* bldh[2]; char* bldl[2];
#pragma unroll
  for (int i = 0; i < 2; ++i) {
    int o = w * 2048 + i * 1024 + lane * 16;
    int row = o >> 6, k2 = o & 63;
    bcsw[i] = k2 ^ (((row >> 1) & 3) << 4);
    browh[i] = (const char*)Bh + (size_t)(n0 + row) * ldb * 2;
    browl[i] = (const char*)Bl + (size_t)(n0 + row) * ldb * 2;
    bldh[i] = (char*)Bhs + (o - lane * 16);
    bldl[i] = (char*)Bls + (o - lane * 16);
  }

  // ---- A staging precompute ----
  const char* arof[4]; int acswf[4]; char* aldf[4];                       // fp32
  const char* aroh[2]; const char* arol[2]; int acswp[2]; char* aldh[2]; char* aldl[2]; // planes
  if constexpr (AFP32) {
#pragma unroll
    for (int i = 0; i < 4; ++i) {
      int o = w * 4096 + i * 1024 + lane * 16;
      int row = o >> 7, k2 = o & 127;
      int rg = m0 + row; if (rg > M - 1) rg = M - 1;    // row clamp (dup row ok)
      acswf[i] = k2 ^ ((row & 7) << 4);
      arof[i] = (const char*)Af + (size_t)rg * lda * 4;
      aldf[i] = (char*)As + (o - lane * 16);
    }
  } else {
#pragma unroll
    for (int i = 0; i < 2; ++i) {
      int o = w * 2048 + i * 1024 + lane * 16;
      int row = o >> 6, k2 = o & 63;
      int rg = m0 + row; if (rg > M - 1) rg = M - 1;
      acswp[i] = k2 ^ (((row >> 1) & 3) << 4);
      aroh[i] = (const char*)Aph + (size_t)rg * lda * 2;
      arol[i] = (const char*)Apl + (size_t)rg * lda * 2;
      aldh[i] = (char*)Ahs + (o - lane * 16);
      aldl[i] = (char*)Als + (o - lane * 16);
    }
  }

  // ---- fragment LDS read offsets (kk-invariant) ----
  const int r16 = lane & 15, kh = lane >> 4;
  const int wr = (w >> 1) * 64, wc = (w & 1) * 64;
  int aoff0[4], aoff1[4], aoffp[4], boff[4];
#pragma unroll
  for (int m = 0; m < 4; ++m) {
    int row = wr + m * 16 + r16;
    if constexpr (AFP32) {
      int s = (row & 7) << 4;
      aoff0[m] = row * 128 + ((kh * 32) ^ s);
      aoff1[m] = row * 128 + ((kh * 32 + 16) ^ s);
    } else {
      aoffp[m] = row * 64 + ((kh * 16) ^ (((row >> 1) & 3) << 4));
    }
  }
#pragma unroll
  for (int n = 0; n < 4; ++n) {
    int row = wc + n * 16 + r16;
    boff[n] = row * 64 + ((kh * 16) ^ (((row >> 1) & 3) << 4));
  }

  const int K4m16 = AFP32 ? (K * 4 - 16) : 0;

  f32x4 acc[4][4];
#pragma unroll
  for (int m = 0; m < 4; ++m)
#pragma unroll
    for (int n = 0; n < 4; ++n) acc[m][n] = (f32x4){0.f, 0.f, 0.f, 0.f};

  for (int kk = k0; kk < k1; ++kk) {
    if constexpr (AFP32) {
#pragma unroll
      for (int i = 0; i < 4; ++i) {
        int colb = kk * 128 + acswf[i];
        if (colb > K4m16) colb = K4m16;      // clamp; B's zero pad kills garbage
        load_lds16(arof[i] + colb, aldf[i]);
      }
    } else {
#pragma unroll
      for (int i = 0; i < 2; ++i) {
        int colb = kk * 64 + acswp[i];
        load_lds16(aroh[i] + colb, aldh[i]);
        load_lds16(arol[i] + colb, aldl[i]);
      }
    }
#pragma unroll
    for (int i = 0; i < 2; ++i) {
      int colb = kk * 64 + bcsw[i];
      load_lds16(browh[i] + colb, bldh[i]);
      load_lds16(browl[i] + colb, bldl[i]);
    }
    __syncthreads();

    bf16x8 ah[4], al[4], bh[4], bl[4];
    if constexpr (AFP32) {
#pragma unroll
      for (int m = 0; m < 4; ++m) {
        f32x4 q0 = *(const f32x4*)((const char*)As + aoff0[m]);
        f32x4 q1 = *(const f32x4*)((const char*)As + aoff1[m]);
        BFU ua, ul;
        split_pair(q0[0], q0[1], ua.u[0], ul.u[0]);
        split_pair(q0[2], q0[3], ua.u[1], ul.u[1]);
        split_pair(q1[0], q1[1], ua.u[2], ul.u[2]);
        split_pair(q1[2], q1[3], ua.u[3], ul.u[3]);
        ah[m] = ua.v; al[m] = ul.v;
      }
    } else {
#pragma unroll
      for (int m = 0; m < 4; ++m) {
        ah[m] = *(const bf16x8*)((const char*)Ahs + aoffp[m]);
        al[m] = *(const bf16x8*)((const char*)Als + aoffp[m]);
      }
    }
#pragma unroll
    for (int n = 0; n < 4; ++n) {
      bh[n] = *(const bf16x8*)((const char*)Bhs + boff[n]);
      bl[n] = *(const bf16x8*)((const char*)Bls + boff[n]);
    }
#pragma unroll
    for (int m = 0; m < 4; ++m)
#pragma unroll
      for (int n = 0; n < 4; ++n) {
        acc[m][n] = __builtin_amdgcn_mfma_f32_16x16x32_bf16(ah[m], bh[n], acc[m][n], 0, 0, 0);
        acc[m][n] = __builtin_amdgcn_mfma_f32_16x16x32_bf16(ah[m], bl[n], acc[m][n], 0, 0, 0);
        acc[m][n] = __builtin_amdgcn_mfma_f32_16x16x32_bf16(al[m], bh[n], acc[m][n], 0, 0, 0);
      }
    __syncthreads();
  }

  float* Cpart = Cp + (size_t)part * (size_t)M * N;
#pragma unroll
  for (int m = 0; m < 4; ++m) {
    int rbase = m0 + wr + m * 16 + kh * 4;
#pragma unroll
    for (int n = 0; n < 4; ++n) {
      int c = n0 + wc + n * 16 + r16;
#pragma unroll
      for (int j = 0; j < 4; ++j) {
        int rr = rbase + j;
        if (rr < M && c < N) Cpart[(size_t)rr * N + c] = acc[m][n][j];
      }
    }
  }
}

// ---------------------------------------------------------------------------
// h = x*mask -> bf16 hi/lo planes [10000][2016] (zero-padded cols)
// ---------------------------------------------------------------------------
__global__ void k_mulmask_planes(const float* __restrict__ x, const float* __restrict__ mask,
                                 unsigned short* __restrict__ Hh, unsigned short* __restrict__ Hl)
{
  int c4 = blockIdx.x * 256 + threadIdx.x;   // handles 4 cols
  int r = blockIdx.y;
  if (c4 >= 504) return;
  int c = c4 * 4;
  uint2 ph = {0u, 0u}, pl = {0u, 0u};
  if (c < 2000) {
    const float4 xv = *(const float4*)(x + (size_t)r * 2000 + c);
    const float4 mv = *(const float4*)(mask + (size_t)r * 2000 + c);
    split_pair(xv.x * mv.x, xv.y * mv.y, ph.x, pl.x);
    split_pair(xv.z * mv.z, xv.w * mv.w, ph.y, pl.y);
  }
  *(uint2*)(Hh + (size_t)r * 2016 + c) = ph;
  *(uint2*)(Hl + (size_t)r * 2016 + c) = pl;
}

// ---------------------------------------------------------------------------
// Sum partials, transpose, split into bf16 hi/lo planes T[rowsOut][ldk].
// Zero-fills r>=M (K pad) and c>=N.  block (32,8)
// ---------------------------------------------------------------------------
__global__ void k_transpose_split(const float* __restrict__ P, int parts, int M, int N,
                                  unsigned short* __restrict__ Th, unsigned short* __restrict__ Tl,
                                  int ldk, int rowsOut)
{
  __shared__ float tile[32][33];
  int kb = blockIdx.x * 32;
  int nb = blockIdx.y * 32;
  int tx = threadIdx.x, ty = threadIdx.y;
#pragma unroll
  for (int i = 0; i < 4; ++i) {
    int rr = kb + ty + i * 8;
    int c = nb + tx;
    float v = 0.f;
    if (rr < M && c < N) {
      size_t idx = (size_t)rr * N + c;
      v = P[idx];
      for (int p = 1; p < parts; ++p) v += P[(size_t)p * M * N + idx];
    }
    tile[ty + i * 8][tx] = v;
  }
  __syncthreads();
#pragma unroll
  for (int i = 0; i < 4; ++i) {
    int tr = nb + ty + i * 8;
    int tc = kb + tx;
    if (tr < rowsOut && tc < ldk) {
      float v = tile[tx][ty + i * 8];
      unsigned short hb = f2bf(v);
      size_t o = (size_t)tr * ldk + tc;
      Th[o] = hb;
      Tl[o] = f2bf(v - bf2f(hb));
    }
  }
}

// ---------------------------------------------------------------------------
// activations: v = relu?(sum parts + bias) -> bf16 hi/lo planes [M][N]
// ---------------------------------------------------------------------------
__global__ void k_finish_planes(const float* __restrict__ P, int parts,
                                const float* __restrict__ bias, int relu,
                                unsigned short* __restrict__ Oh, unsigned short* __restrict__ Ol,
                                int M, int N)
{
  int c = blockIdx.x * 256 + threadIdx.x;
  int r = blockIdx.y;
  if (c >= N) return;
  size_t idx = (size_t)r * N + c;
  float v = P[idx];
  for (int p = 1; p < parts; ++p) v += P[(size_t)p * M * N + idx];
  v += bias[c];
  if (relu) v = fmaxf(v, 0.f);
  unsigned short hb = f2bf(v);
  Oh[idx] = hb;
  Ol[idx] = f2bf(v - bf2f(hb));
}

// ---------------------------------------------------------------------------
// z = (sum parts + bz) row-normalized -> d_out fp32 AND bf16 hi/lo planes
// ---------------------------------------------------------------------------
__global__ void k_finish_z(const float* __restrict__ P, int parts, const float* __restrict__ bz,
                           float* __restrict__ zout,
                           unsigned short* __restrict__ Zh, unsigned short* __restrict__ Zl)
{
  int r = blockIdx.x, c = threadIdx.x;
  size_t idx = (size_t)r * 128 + c;
  float v = P[idx];
  for (int p = 1; p < parts; ++p) v += P[(size_t)p * 10000 * 128 + idx];
  v += bz[c];
  float s = v * v;
#pragma unroll
  for (int off = 32; off > 0; off >>= 1) s += __shfl_down(s, off, 64);
  __shared__ float red[2];
  if ((c & 63) == 0) red[c >> 6] = s;
  __syncthreads();
  float inv = 1.f / fmaxf(sqrtf(red[0] + red[1]), 1e-12f);
  float z = v * inv;
  zout[idx] = z;
  unsigned short hb = f2bf(z);
  Zh[idx] = hb;
  Zl[idx] = f2bf(z - bf2f(hb));
}

// ---------------------------------------------------------------------------
// x_hat = (P + bd2) * mask
// ---------------------------------------------------------------------------
__global__ void k_finish_xhat(const float* __restrict__ P, const float* __restrict__ bd2,
                              const float* __restrict__ mask, float* __restrict__ out)
{
  int c = blockIdx.x * 256 + threadIdx.x;
  int r = blockIdx.y;
  if (c >= 2000) return;
  size_t idx = (size_t)r * 2000 + c;
  out[idx] = (P[idx] + bd2[c]) * mask[idx];
}

// ---------------------------------------------------------------------------
extern "C" void kernel_launch(void* const* d_in, const int* in_sizes, int n_in,
                              void* d_out, int out_size, void* d_ws, size_t ws_size,
                              hipStream_t stream)
{
  (void)in_sizes; (void)n_in; (void)out_size; (void)ws_size;
  const float* x    = (const float*)d_in[0];
  const float* adj  = (const float*)d_in[1];
  const float* mask = (const float*)d_in[2];
  const float* We0  = (const float*)d_in[3];
  const float* be0  = (const float*)d_in[4];
  const float* We1  = (const float*)d_in[5];
  const float* be1  = (const float*)d_in[6];
  const float* Wz   = (const float*)d_in[7];
  const float* bz   = (const float*)d_in[8];
  const float* Wd0  = (const float*)d_in[9];
  const float* bd0  = (const float*)d_in[10];
  const float* Wd1  = (const float*)d_in[11];
  const float* bd1  = (const float*)d_in[12];
  const float* Wd2  = (const float*)d_in[13];
  const float* bd2  = (const float*)d_in[14];

  char* wsp = (char*)d_ws;
  size_t off = 0;
  auto alloc = [&](size_t bytes) -> char* {
    char* p = wsp + off; off += (bytes + 255) & ~(size_t)255; return p;
  };

  // h-region: Hh/Hl planes; later reused as big partial arena, then G8 partial
  unsigned short* Hh = (unsigned short*)alloc((size_t)10000 * 2016 * 2);
  unsigned short* Hl = (unsigned short*)alloc((size_t)10000 * 2016 * 2);
  float* arenaBig = (float*)Hh;    // 80.6 MB region (>= 41 MB max partials)
  float* g8p      = (float*)Hh;    // 80 MB G8 partial

  unsigned short* We0Th = (unsigned short*)alloc((size_t)512 * 2016 * 2);
  unsigned short* We0Tl = (unsigned short*)alloc((size_t)512 * 2016 * 2);
  unsigned short* We1Th = (unsigned short*)alloc((size_t)256 * 512 * 2);
  unsigned short* We1Tl = (unsigned short*)alloc((size_t)256 * 512 * 2);
  unsigned short* WzTh  = (unsigned short*)alloc((size_t)128 * 256 * 2);
  unsigned short* WzTl  = (unsigned short*)alloc((size_t)128 * 256 * 2);
  unsigned short* Wd0Th = (unsigned short*)alloc((size_t)256 * 128 * 2);
  unsigned short* Wd0Tl = (unsigned short*)alloc((size_t)256 * 128 * 2);
  unsigned short* Wd1Th = (unsigned short*)alloc((size_t)512 * 256 * 2);
  unsigned short* Wd1Tl = (unsigned short*)alloc((size_t)512 * 256 * 2);
  unsigned short* Wd2Th = (unsigned short*)alloc((size_t)2048 * 512 * 2);
  unsigned short* Wd2Tl = (unsigned short*)alloc((size_t)2048 * 512 * 2);
  unsigned short* t0Th  = (unsigned short*)alloc((size_t)512 * 10016 * 2);
  unsigned short* t0Tl  = (unsigned short*)alloc((size_t)512 * 10016 * 2);
  unsigned short* t1Th  = (unsigned short*)alloc((size_t)256 * 10016 * 2);
  unsigned short* t1Tl  = (unsigned short*)alloc((size_t)256 * 10016 * 2);
  unsigned short* tzTh  = (unsigned short*)alloc((size_t)128 * 10016 * 2);
  unsigned short* tzTl  = (unsigned short*)alloc((size_t)128 * 10016 * 2);
  // activation planes, contiguous; head doubles as G0's 41 MB partial arena
  unsigned short* h0h = (unsigned short*)alloc((size_t)10000 * 512 * 2);
  unsigned short* h0l = (unsigned short*)alloc((size_t)10000 * 512 * 2);
  unsigned short* h1h = (unsigned short*)alloc((size_t)10000 * 256 * 2);
  unsigned short* h1l = (unsigned short*)alloc((size_t)10000 * 256 * 2);
  unsigned short* d0h = (unsigned short*)alloc((size_t)10000 * 256 * 2);
  unsigned short* d0l = (unsigned short*)alloc((size_t)10000 * 256 * 2);
  unsigned short* d1h = (unsigned short*)alloc((size_t)10000 * 512 * 2);
  unsigned short* d1l = (unsigned short*)alloc((size_t)10000 * 512 * 2);
  unsigned short* zh  = (unsigned short*)alloc((size_t)10000 * 128 * 2);
  unsigned short* zl  = (unsigned short*)alloc((size_t)10000 * 128 * 2);
  float* arena1 = (float*)h0h;     // G0 partials (2x20.5 MB), dead before h0 written

  float* zout    = (float*)d_out;
  float* xhat    = zout + (size_t)10000 * 128;
  float* maskout = xhat + (size_t)10000 * 2000;

  dim3 b256(256), b32x8(32, 8);

  k_mulmask_planes<<<dim3(2, 10000), b256, 0, stream>>>(x, mask, Hh, Hl);

  k_transpose_split<<<dim3(63, 16), b32x8, 0, stream>>>(We0, 1, 2000, 512, We0Th, We0Tl, 2016, 512);
  k_transpose_split<<<dim3(16, 8),  b32x8, 0, stream>>>(We1, 1, 512, 256, We1Th, We1Tl, 512, 256);
  k_transpose_split<<<dim3(8, 4),   b32x8, 0, stream>>>(Wz,  1, 256, 128, WzTh,  WzTl,  256, 128);
  k_transpose_split<<<dim3(4, 8),   b32x8, 0, stream>>>(Wd0, 1, 128, 256, Wd0Th, Wd0Tl, 128, 256);
  k_transpose_split<<<dim3(8, 16),  b32x8, 0, stream>>>(Wd1, 1, 256, 512, Wd1Th, Wd1Tl, 256, 512);
  k_transpose_split<<<dim3(16, 64), b32x8, 0, stream>>>(Wd2, 1, 512, 2000, Wd2Th, Wd2Tl, 512, 2048);

  // G0: t0 = h @ We0   [10000,512]  (A planes, splitK 2 -> arena1)
  k_gemm<false><<<dim3(632), b256, 0, stream>>>(nullptr, 0, Hh, Hl, 2016, We0Th, We0Tl, 2016,
                                                arena1, 10000, 512, 63, 79, 4, 32);
  k_transpose_split<<<dim3(313, 16), b32x8, 0, stream>>>(arena1, 2, 10000, 512, t0Th, t0Tl, 10016, 512);

  // G1: h0 = relu(adj @ t0 + be0)   (fp32 A, splitK 2)
  k_gemm<true><<<dim3(632), b256, 0, stream>>>(adj, 10000, nullptr, nullptr, 10000, t0Th, t0Tl, 10016,
                                               arenaBig, 10000, 512, 313, 79, 4, 157);
  k_finish_planes<<<dim3(2, 10000), b256, 0, stream>>>(arenaBig, 2, be0, 1, h0h, h0l, 10000, 512);

  // G2: t1 = h0 @ We1   [10000,256]  (splitK 2)
  k_gemm<false><<<dim3(316), b256, 0, stream>>>(nullptr, 0, h0h, h0l, 512, We1Th, We1Tl, 512,
                                                arenaBig, 10000, 256, 16, 79, 2, 8);
  k_transpose_split<<<dim3(313, 8), b32x8, 0, stream>>>(arenaBig, 2, 10000, 256, t1Th, t1Tl, 10016, 256);

  // G3: h1 = relu(adj @ t1 + be1)   (splitK 4)
  k_gemm<true><<<dim3(632), b256, 0, stream>>>(adj, 10000, nullptr, nullptr, 10000, t1Th, t1Tl, 10016,
                                               arenaBig, 10000, 256, 313, 79, 2, 79);
  k_finish_planes<<<dim3(1, 10000), b256, 0, stream>>>(arenaBig, 4, be1, 1, h1h, h1l, 10000, 256);

  // G4: tz = h1 @ Wz   [10000,128]  (splitK 4)
  k_gemm<false><<<dim3(316), b256, 0, stream>>>(nullptr, 0, h1h, h1l, 256, WzTh, WzTl, 256,
                                                arenaBig, 10000, 128, 8, 79, 1, 2);
  k_transpose_split<<<dim3(313, 4), b32x8, 0, stream>>>(arenaBig, 4, 10000, 128, tzTh, tzTl, 10016, 128);

  // G5: z = normalize(adj @ tz + bz)   (splitK 8)
  k_gemm<true><<<dim3(632), b256, 0, stream>>>(adj, 10000, nullptr, nullptr, 10000, tzTh, tzTl, 10016,
                                               arenaBig, 10000, 128, 313, 79, 1, 40);
  k_finish_z<<<dim3(10000), dim3(128), 0, stream>>>(arenaBig, 8, bz, zout, zh, zl);

  // G6: d0 = relu(z @ Wd0 + bd0)   [10000,256]  (splitK 2)
  k_gemm<false><<<dim3(316), b256, 0, stream>>>(nullptr, 0, zh, zl, 128, Wd0Th, Wd0Tl, 128,
                                                arenaBig, 10000, 256, 4, 79, 2, 2);
  k_finish_planes<<<dim3(1, 10000), b256, 0, stream>>>(arenaBig, 2, bd0, 1, d0h, d0l, 10000, 256);

  // G7: d1 = relu(d0 @ Wd1 + bd1)   [10000,512]
  k_gemm<false><<<dim3(316), b256, 0, stream>>>(nullptr, 0, d0h, d0l, 256, Wd1Th, Wd1Tl, 256,
                                                arenaBig, 10000, 512, 8, 79, 4, 8);
  k_finish_planes<<<dim3(2, 10000), b256, 0, stream>>>(arenaBig, 1, bd1, 1, d1h, d1l, 10000, 512);

  // G8: x_hat = (d1 @ Wd2 + bd2) * mask   [10000,2000]
  k_gemm<false><<<dim3(1264), b256, 0, stream>>>(nullptr, 0, d1h, d1l, 512, Wd2Th, Wd2Tl, 512,
                                                 g8p, 10000, 2000, 16, 79, 16, 16);
  k_finish_xhat<<<dim3(8, 10000), b256, 0, stream>>>(g8p, bd2, mask, xhat);

  hipMemcpyAsync(maskout, mask, (size_t)10000 * 2000 * 4, hipMemcpyDeviceToDevice, stream);
}